// Round 1
// baseline (1736.400 us; speedup 1.0000x reference)
//
#include <hip/hip_runtime.h>
#include <math.h>

#define HH 128
#define WW 128
#define HWSZ 16384
#define OCH 128

// ---------------- weight transpose: w[o][ck] -> wt[ck][o] ----------------
__global__ void transpose_w(const float* __restrict__ w, float* __restrict__ wt,
                            int O, int CK) {
    int i = blockIdx.x * blockDim.x + threadIdx.x;
    if (i < O * CK) {
        int o = i / CK, ck = i % CK;
        wt[ck * O + o] = w[i];
    }
}

// ---------------- fused offset+modulation 3x3 conv ----------------
// out channels: 0..17 = offsets (dy=2k, dx=2k+1), 18..26 = modulation
// block: 128 threads = one image row; grid: B*H
template <int C>
__global__ __launch_bounds__(128) void offmod_conv(
    const float* __restrict__ x, const float* __restrict__ w_off,
    const float* __restrict__ b_off, const float* __restrict__ w_mod,
    const float* __restrict__ b_mod, float* __restrict__ dyb,
    float* __restrict__ dxb, float* __restrict__ mob) {
    int bh = blockIdx.x;
    int b = bh / HH;
    int h = bh % HH;
    int w = threadIdx.x;

    float acc[27];
#pragma unroll
    for (int i = 0; i < 27; ++i) acc[i] = 0.f;

    const float* xb = x + (size_t)b * C * HWSZ;
    for (int c = 0; c < C; ++c) {
        const float* xc = xb + c * HWSZ;
        const float* wo = w_off + c * 9;   // [oc][c][t], oc stride C*9
        const float* wm = w_mod + c * 9;
#pragma unroll
        for (int ky = 0; ky < 3; ++ky) {
            int yy = h + ky - 1;
            bool yok = (yy >= 0) && (yy < HH);
#pragma unroll
            for (int kx = 0; kx < 3; ++kx) {
                int xx = w + kx - 1;
                float v = 0.f;
                if (yok && xx >= 0 && xx < WW) v = xc[yy * WW + xx];
                int t = ky * 3 + kx;
#pragma unroll
                for (int oc = 0; oc < 18; ++oc)
                    acc[oc] += v * wo[oc * C * 9 + t];
#pragma unroll
                for (int oc = 0; oc < 9; ++oc)
                    acc[18 + oc] += v * wm[oc * C * 9 + t];
            }
        }
    }

    int hw = h * WW + w;
#pragma unroll
    for (int k = 0; k < 9; ++k) {
        int oi = (b * 9 + k) * HWSZ + hw;
        dyb[oi] = acc[2 * k] + b_off[2 * k];
        dxb[oi] = acc[2 * k + 1] + b_off[2 * k + 1];
        float mv = acc[18 + k] + b_mod[k];
        mob[oi] = 2.f / (1.f + expf(-mv));
    }
}

// ---------------- deformable conv main (implicit GEMM) ----------------
// block: 256 threads handles PIX pixels x all 128 output channels.
// phase 1: bilinear gather of patch P[ck][p] into LDS (mod folded in)
// phase 2: dot with Wt[ck][o]
template <int C, int PIX>
__global__ __launch_bounds__(256) void deform_main(
    const float* __restrict__ x, const float* __restrict__ dyb,
    const float* __restrict__ dxb, const float* __restrict__ mob,
    const float* __restrict__ Wt, float* __restrict__ out) {
    constexpr int CK = C * 9;
    constexpr int NPG = PIX / 2;
    __shared__ float patch[CK * PIX];
    __shared__ int cidx[PIX * 9 * 4];
    __shared__ float cwt[PIX * 9 * 4];

    int m0 = blockIdx.x * PIX;
    int b = m0 / HWSZ;  // uniform (PIX divides HW)
    int t = threadIdx.x;

    if (t < PIX * 9) {
        int p = t / 9, k = t % 9;
        int m = m0 + p;
        int hw = m % HWSZ;
        int h = hw / WW, w = hw % WW;
        int oi = (b * 9 + k) * HWSZ + hw;
        float py = (float)(h + k / 3 - 1) + dyb[oi];
        float px = (float)(w + k % 3 - 1) + dxb[oi];
        float mv = mob[oi];
        float y0f = floorf(py), x0f = floorf(px);
        int y0 = (int)y0f, x0 = (int)x0f;
        float wy = py - y0f, wx = px - x0f;
        int y1 = y0 + 1, x1 = x0 + 1;
        float w00 = (1.f - wy) * (1.f - wx), w01 = (1.f - wy) * wx;
        float w10 = wy * (1.f - wx), w11 = wy * wx;
        bool v0y = (y0 >= 0) && (y0 < HH), v1y = (y1 >= 0) && (y1 < HH);
        bool v0x = (x0 >= 0) && (x0 < WW), v1x = (x1 >= 0) && (x1 < WW);
        int cy0 = min(max(y0, 0), HH - 1), cy1 = min(max(y1, 0), HH - 1);
        int cx0 = min(max(x0, 0), WW - 1), cx1 = min(max(x1, 0), WW - 1);
        int base = t * 4;
        cidx[base + 0] = cy0 * WW + cx0;
        cwt[base + 0] = w00 * ((v0y && v0x) ? 1.f : 0.f) * mv;
        cidx[base + 1] = cy0 * WW + cx1;
        cwt[base + 1] = w01 * ((v0y && v1x) ? 1.f : 0.f) * mv;
        cidx[base + 2] = cy1 * WW + cx0;
        cwt[base + 2] = w10 * ((v1y && v0x) ? 1.f : 0.f) * mv;
        cidx[base + 3] = cy1 * WW + cx1;
        cwt[base + 3] = w11 * ((v1y && v1x) ? 1.f : 0.f) * mv;
    }
    __syncthreads();

    const float* xb = x + (size_t)b * C * HWSZ;
    for (int e = t; e < CK * PIX; e += 256) {
        int ck = e / PIX, p = e % PIX;
        int c = ck / 9, k = ck - ck / 9 * 9;
        int base = (p * 9 + k) * 4;
        const float* xc = xb + c * HWSZ;
        float v = cwt[base + 0] * xc[cidx[base + 0]] +
                  cwt[base + 1] * xc[cidx[base + 1]] +
                  cwt[base + 2] * xc[cidx[base + 2]] +
                  cwt[base + 3] * xc[cidx[base + 3]];
        patch[e] = v;  // e == ck*PIX + p
    }
    __syncthreads();

    int o = t & 127, g = t >> 7;
    float acc[NPG];
#pragma unroll
    for (int i = 0; i < NPG; ++i) acc[i] = 0.f;
    for (int ck = 0; ck < CK; ++ck) {
        float wv = Wt[ck * OCH + o];
        const float* pp = &patch[ck * PIX + g * NPG];
#pragma unroll
        for (int i = 0; i < NPG; ++i) acc[i] += pp[i] * wv;
    }
#pragma unroll
    for (int i = 0; i < NPG; ++i) {
        int m = m0 + g * NPG + i;
        int hw = m % HWSZ;
        out[((size_t)(b * OCH + o)) * HWSZ + hw] = acc[i];
    }
}

// ---------------- batchnorm stats: one block per channel ----------------
__global__ __launch_bounds__(256) void bn_stats(const float* __restrict__ xin,
                                                float* __restrict__ stats,
                                                int B, int C) {
    int c = blockIdx.x;
    float s = 0.f, sq = 0.f;
    for (int b = 0; b < B; ++b) {
        const float* p = xin + ((size_t)(b * C + c)) * HWSZ;
        for (int i = threadIdx.x; i < HWSZ; i += blockDim.x) {
            float v = p[i];
            s += v;
            sq += v * v;
        }
    }
    __shared__ float ls[256], lq[256];
    ls[threadIdx.x] = s;
    lq[threadIdx.x] = sq;
    __syncthreads();
    for (int st = 128; st > 0; st >>= 1) {
        if (threadIdx.x < st) {
            ls[threadIdx.x] += ls[threadIdx.x + st];
            lq[threadIdx.x] += lq[threadIdx.x + st];
        }
        __syncthreads();
    }
    if (threadIdx.x == 0) {
        float N = (float)(B * HWSZ);
        float mean = ls[0] / N;
        float var = lq[0] / N - mean * mean;
        stats[c] = mean;
        stats[C + c] = rsqrtf(var + 1e-5f);
    }
}

// ---------------- bn normalize + relu (in place) ----------------
__global__ __launch_bounds__(256) void bn_apply(float* __restrict__ x,
                                                const float* __restrict__ stats,
                                                int total, int C) {
    int i = blockIdx.x * blockDim.x + threadIdx.x;
    int n4 = total / 4;
    if (i < n4) {
        float4 v = ((float4*)x)[i];
        int c = ((i * 4) / HWSZ) % C;
        float mean = stats[c], rstd = stats[C + c];
        v.x = fmaxf(0.f, (v.x - mean) * rstd);
        v.y = fmaxf(0.f, (v.y - mean) * rstd);
        v.z = fmaxf(0.f, (v.z - mean) * rstd);
        v.w = fmaxf(0.f, (v.w - mean) * rstd);
        ((float4*)x)[i] = v;
    }
}

// ---------------- fused bn + relu + 2x2 maxpool ----------------
// relu(norm(max)) == max(relu(norm())) since norm is affine increasing
__global__ __launch_bounds__(256) void bn_pool(const float* __restrict__ x,
                                               const float* __restrict__ stats,
                                               float* __restrict__ out, int B,
                                               int C) {
    const int Ho = 64, Wo = 64;
    int i = blockIdx.x * blockDim.x + threadIdx.x;
    int total = B * C * Ho * Wo;
    if (i >= total) return;
    int ow = i % Wo;
    int t = i / Wo;
    int oh = t % Ho;
    t /= Ho;
    int c = t % C;
    int b = t / C;
    const float* p = x + ((size_t)(b * C + c)) * HWSZ + (2 * oh) * WW + 2 * ow;
    float m0 = fmaxf(p[0], p[1]);
    float m1 = fmaxf(p[WW], p[WW + 1]);
    float mx = fmaxf(m0, m1);
    out[i] = fmaxf(0.f, (mx - stats[c]) * stats[C + c]);
}

extern "C" void kernel_launch(void* const* d_in, const int* in_sizes, int n_in,
                              void* d_out, int out_size, void* d_ws,
                              size_t ws_size, hipStream_t stream) {
    (void)in_sizes;
    (void)n_in;
    (void)out_size;
    (void)ws_size;
    const float* x = (const float*)d_in[0];
    const float* w_off1 = (const float*)d_in[1];
    const float* b_off1 = (const float*)d_in[2];
    const float* w_mod1 = (const float*)d_in[3];
    const float* b_mod1 = (const float*)d_in[4];
    const float* w1 = (const float*)d_in[5];
    const float* w_off2 = (const float*)d_in[6];
    const float* b_off2 = (const float*)d_in[7];
    const float* w_mod2 = (const float*)d_in[8];
    const float* b_mod2 = (const float*)d_in[9];
    const float* w2 = (const float*)d_in[10];
    float* out = (float*)d_out;
    float* ws = (float*)d_ws;

    float* Wt1 = ws;                  // 576*128   = 73728
    float* Wt2 = Wt1 + 73728;         // 1152*128  = 147456
    float* dyb = Wt2 + 147456;        // 4*9*16384 = 589824
    float* dxb = dyb + 589824;
    float* mob = dxb + 589824;
    float* h1 = mob + 589824;         // 4*128*16384 = 8388608
    float* h2 = h1 + 8388608;
    float* st = h2 + 8388608;         // 256

    transpose_w<<<(73728 + 255) / 256, 256, 0, stream>>>(w1, Wt1, 128, 576);
    transpose_w<<<(147456 + 255) / 256, 256, 0, stream>>>(w2, Wt2, 128, 1152);

    // ---- stage 1 ----
    offmod_conv<64><<<512, 128, 0, stream>>>(x, w_off1, b_off1, w_mod1, b_mod1,
                                             dyb, dxb, mob);
    deform_main<64, 16><<<4096, 256, 0, stream>>>(x, dyb, dxb, mob, Wt1, h1);
    bn_stats<<<128, 256, 0, stream>>>(h1, st, 4, 128);
    bn_apply<<<8192, 256, 0, stream>>>(h1, st, 4 * 128 * HWSZ, 128);

    // ---- stage 2 ----
    offmod_conv<128><<<512, 128, 0, stream>>>(h1, w_off2, b_off2, w_mod2,
                                              b_mod2, dyb, dxb, mob);
    deform_main<128, 8><<<8192, 256, 0, stream>>>(h1, dyb, dxb, mob, Wt2, h2);
    bn_stats<<<128, 256, 0, stream>>>(h2, st, 4, 128);
    bn_pool<<<8192, 256, 0, stream>>>(h2, st, out, 4, 128);
}

// Round 2
// 1286.215 us; speedup vs baseline: 1.3500x; 1.3500x over previous
//
#include <hip/hip_runtime.h>
#include <math.h>

#define HH 128
#define WW 128
#define HWSZ 16384

typedef __attribute__((ext_vector_type(8))) short short8;
typedef __attribute__((ext_vector_type(4))) float f32x4;
typedef unsigned short ushort;

__device__ __forceinline__ ushort f2bf(float f) {
    unsigned int u = __float_as_uint(f);
    unsigned int r = u + 0x7fffu + ((u >> 16) & 1u);
    return (ushort)(r >> 16);
}

// ---- weight transpose+pad: w[o][c][k] -> wt[o][k*(C+8)+c] bf16, K padded to KP ----
__global__ void transpose_wpad(const float* __restrict__ w, ushort* __restrict__ wt,
                               int C, int CP, int KP) {
    int i = blockIdx.x * 256 + threadIdx.x;
    if (i >= 128 * KP) return;
    int o = i / KP, kq = i % KP;
    int k = kq / CP, c = kq % CP;
    float v = (k < 9 && c < C) ? w[(o * C + c) * 9 + k] : 0.f;
    wt[i] = f2bf(v);
}

// ---- fused offset+modulation 3x3 conv (unchanged from R0) ----
template <int C>
__global__ __launch_bounds__(128) void offmod_conv(
    const float* __restrict__ x, const float* __restrict__ w_off,
    const float* __restrict__ b_off, const float* __restrict__ w_mod,
    const float* __restrict__ b_mod, float* __restrict__ dyb,
    float* __restrict__ dxb, float* __restrict__ mob) {
    int bh = blockIdx.x;
    int b = bh / HH;
    int h = bh % HH;
    int w = threadIdx.x;

    float acc[27];
#pragma unroll
    for (int i = 0; i < 27; ++i) acc[i] = 0.f;

    const float* xb = x + (size_t)b * C * HWSZ;
    for (int c = 0; c < C; ++c) {
        const float* xc = xb + c * HWSZ;
        const float* wo = w_off + c * 9;
        const float* wm = w_mod + c * 9;
#pragma unroll
        for (int ky = 0; ky < 3; ++ky) {
            int yy = h + ky - 1;
            bool yok = (yy >= 0) && (yy < HH);
#pragma unroll
            for (int kx = 0; kx < 3; ++kx) {
                int xx = w + kx - 1;
                float v = 0.f;
                if (yok && xx >= 0 && xx < WW) v = xc[yy * WW + xx];
                int t = ky * 3 + kx;
#pragma unroll
                for (int oc = 0; oc < 18; ++oc)
                    acc[oc] += v * wo[oc * C * 9 + t];
#pragma unroll
                for (int oc = 0; oc < 9; ++oc)
                    acc[18 + oc] += v * wm[oc * C * 9 + t];
            }
        }
    }

    int hw = h * WW + w;
#pragma unroll
    for (int k = 0; k < 9; ++k) {
        int oi = (b * 9 + k) * HWSZ + hw;
        dyb[oi] = acc[2 * k] + b_off[2 * k];
        dxb[oi] = acc[2 * k + 1] + b_off[2 * k + 1];
        float mv = acc[18 + k] + b_mod[k];
        mob[oi] = 2.f / (1.f + expf(-mv));
    }
}

// ---- deformable conv: lane-coherent gather + bf16 MFMA implicit GEMM ----
// PIX pixels (one row segment) x 128 outputs per block, 256 threads.
// patch LDS layout: [p][kappa], kappa = k*CP+c, CP=C+8 (bank spread + b128 align),
// K padded to KP (mult of 32) with zero weights. Taps in registers.
template <int C, int PIX>
__global__ __launch_bounds__(256) void deform_mfma(
    const float* __restrict__ x, const float* __restrict__ dyb,
    const float* __restrict__ dxb, const float* __restrict__ mob,
    const ushort* __restrict__ wt, float* __restrict__ out) {
    constexpr int CP = C + 8;
    constexpr int K9 = 9 * CP;
    constexpr int KP = ((K9 + 31) / 32) * 32;
    constexpr int ROWE = KP + 8;  // ROWE/2 % 8 == 4 -> spread b128 reads
    constexpr int MT = PIX / 16;
    constexpr int GG = 256 / PIX;   // gather groups
    constexpr int NP = 9 * C / GG;  // (k,c) pairs per group (=72)

    __shared__ __align__(16) ushort patch[PIX * ROWE];

    const int m0 = blockIdx.x * PIX;
    const int b = m0 >> 14;
    const int hw0 = m0 & 16383;
    const int h = hw0 >> 7, w0 = hw0 & 127;
    const int tid = threadIdx.x;

    // zero the padded regions (c-pad per (p,k), k-tail per p)
    for (int r = tid; r < PIX * 9; r += 256) {
        int p = r / 9, k = r % 9;
        *(uint4*)&patch[p * ROWE + k * CP + C] = uint4{0, 0, 0, 0};
    }
    if (tid < PIX) {
        uint4* t4 = (uint4*)&patch[tid * ROWE + K9];
        t4[0] = uint4{0, 0, 0, 0};
        t4[1] = uint4{0, 0, 0, 0};
        t4[2] = uint4{0, 0, 0, 0};
    }

    // ---- gather: lanes = pixels, loop over (k,c) pairs, taps in registers ----
    {
        const int p = tid % PIX, g = tid / PIX;
        const int w = w0 + p;
        const float* xb = x + ((size_t)b * C << 14);
        ushort* prow = patch + p * ROWE;
        const int pi0 = g * NP, pi1 = pi0 + NP;
        for (int k = pi0 / C; k * C < pi1; ++k) {
            int c0 = (k * C < pi0) ? (pi0 - k * C) : 0;
            int c1 = (pi1 - k * C < C) ? (pi1 - k * C) : C;
            // tap for (p,k)
            int oi = ((b * 9 + k) << 14) + hw0 + p;
            float py = (float)(h + k / 3 - 1) + dyb[oi];
            float px = (float)(w + k % 3 - 1) + dxb[oi];
            float mv = mob[oi];
            float y0f = floorf(py), x0f = floorf(px);
            float wy = py - y0f, wx = px - x0f;
            int y0 = (int)y0f, x0 = (int)x0f;
            int y1 = y0 + 1, x1 = x0 + 1;
            float f00 = (1.f - wy) * (1.f - wx) *
                        (((unsigned)y0 < 128u && (unsigned)x0 < 128u) ? mv : 0.f);
            float f01 = (1.f - wy) * wx *
                        (((unsigned)y0 < 128u && (unsigned)x1 < 128u) ? mv : 0.f);
            float f10 = wy * (1.f - wx) *
                        (((unsigned)y1 < 128u && (unsigned)x0 < 128u) ? mv : 0.f);
            float f11 = wy * wx *
                        (((unsigned)y1 < 128u && (unsigned)x1 < 128u) ? mv : 0.f);
            int cy0 = min(max(y0, 0), 127), cy1 = min(max(y1, 0), 127);
            int cx0 = min(max(x0, 0), 127), cx1 = min(max(x1, 0), 127);
            int i00 = (cy0 << 7) + cx0, i01 = (cy0 << 7) + cx1;
            int i10 = (cy1 << 7) + cx0, i11 = (cy1 << 7) + cx1;
            ushort* pk = prow + k * CP;
#pragma unroll 4
            for (int c = c0; c < c1; ++c) {
                const float* xc = xb + ((size_t)c << 14);
                float v = f00 * xc[i00] + f01 * xc[i01] + f10 * xc[i10] +
                          f11 * xc[i11];
                pk[c] = f2bf(v);
            }
        }
    }
    __syncthreads();

    // ---- MFMA: C[m=pixel][n=outch] = patch(MxK) * Wt^T ----
    const int lane = tid & 63, wv = tid >> 6;
    const int n16 = lane & 15, quad = lane >> 4;

    f32x4 acc[MT][2];
#pragma unroll
    for (int mt = 0; mt < MT; ++mt)
#pragma unroll
        for (int nt = 0; nt < 2; ++nt) acc[mt][nt] = (f32x4){0.f, 0.f, 0.f, 0.f};

    const ushort* ap[MT];
#pragma unroll
    for (int mt = 0; mt < MT; ++mt)
        ap[mt] = patch + (mt * 16 + n16) * ROWE + quad * 8;
    const ushort* bp[2];
#pragma unroll
    for (int nt = 0; nt < 2; ++nt)
        bp[nt] = wt + (size_t)(wv * 32 + nt * 16 + n16) * KP + quad * 8;

    short8 a_c[MT], b_c[2];
#pragma unroll
    for (int mt = 0; mt < MT; ++mt) a_c[mt] = *(const short8*)(ap[mt]);
#pragma unroll
    for (int nt = 0; nt < 2; ++nt) b_c[nt] = *(const short8*)(bp[nt]);

    int kk = 0;
#pragma unroll 1
    for (; kk + 32 < KP; kk += 32) {
        short8 a_n[MT], b_n[2];
#pragma unroll
        for (int mt = 0; mt < MT; ++mt)
            a_n[mt] = *(const short8*)(ap[mt] + kk + 32);
#pragma unroll
        for (int nt = 0; nt < 2; ++nt)
            b_n[nt] = *(const short8*)(bp[nt] + kk + 32);
#pragma unroll
        for (int mt = 0; mt < MT; ++mt)
#pragma unroll
            for (int nt = 0; nt < 2; ++nt)
                acc[mt][nt] = __builtin_amdgcn_mfma_f32_16x16x32_bf16(
                    a_c[mt], b_c[nt], acc[mt][nt], 0, 0, 0);
#pragma unroll
        for (int mt = 0; mt < MT; ++mt) a_c[mt] = a_n[mt];
#pragma unroll
        for (int nt = 0; nt < 2; ++nt) b_c[nt] = b_n[nt];
    }
#pragma unroll
    for (int mt = 0; mt < MT; ++mt)
#pragma unroll
        for (int nt = 0; nt < 2; ++nt)
            acc[mt][nt] = __builtin_amdgcn_mfma_f32_16x16x32_bf16(
                a_c[mt], b_c[nt], acc[mt][nt], 0, 0, 0);

    // ---- epilogue: transpose through LDS, coalesced float4 stores ----
    __syncthreads();
    float* sm = (float*)patch;
    constexpr int SROW = PIX + 1;
#pragma unroll
    for (int mt = 0; mt < MT; ++mt)
#pragma unroll
        for (int nt = 0; nt < 2; ++nt) {
            int o = wv * 32 + nt * 16 + n16;
            int mb = mt * 16 + quad * 4;
#pragma unroll
            for (int r = 0; r < 4; ++r) sm[o * SROW + mb + r] = acc[mt][nt][r];
        }
    __syncthreads();
    {
        int o = tid >> 1, half = tid & 1;
        constexpr int HP = PIX / 2;
        const float* sp = sm + o * SROW + half * HP;
        float* op = out + (((size_t)(b * 128 + o)) << 14) + hw0 + half * HP;
#pragma unroll
        for (int i = 0; i < HP; i += 4) {
            float4 v = make_float4(sp[i], sp[i + 1], sp[i + 2], sp[i + 3]);
            *(float4*)(op + i) = v;
        }
    }
}

// ---- bn stats: split grid + float atomics ----
__global__ __launch_bounds__(256) void zero_stats(float* __restrict__ praw) {
    praw[threadIdx.x] = 0.f;
}

__global__ __launch_bounds__(256) void bn_partial(const float* __restrict__ xin,
                                                  float* __restrict__ praw) {
    int c = blockIdx.x >> 3, s = blockIdx.x & 7;
    float su = 0.f, sq = 0.f;
#pragma unroll
    for (int j = 0; j < 8; ++j) {
        int e = s * 8192 + (j * 256 + threadIdx.x) * 4;
        int b = e >> 14, hw = e & 16383;
        const float4 v =
            *(const float4*)(xin + (((size_t)(b * 128 + c)) << 14) + hw);
        su += v.x + v.y + v.z + v.w;
        sq += v.x * v.x + v.y * v.y + v.z * v.z + v.w * v.w;
    }
#pragma unroll
    for (int off = 32; off > 0; off >>= 1) {
        su += __shfl_down(su, off, 64);
        sq += __shfl_down(sq, off, 64);
    }
    if ((threadIdx.x & 63) == 0) {
        atomicAdd(&praw[c], su);
        atomicAdd(&praw[128 + c], sq);
    }
}

__global__ __launch_bounds__(128) void bn_finalize(const float* __restrict__ praw,
                                                   float* __restrict__ stats) {
    int c = threadIdx.x;
    float N = 65536.f;
    float mean = praw[c] / N;
    float var = praw[128 + c] / N - mean * mean;
    stats[c] = mean;
    stats[128 + c] = rsqrtf(var + 1e-5f);
}

__global__ __launch_bounds__(256) void bn_apply(float* __restrict__ x,
                                                const float* __restrict__ stats,
                                                int total, int C) {
    int i = blockIdx.x * blockDim.x + threadIdx.x;
    int n4 = total / 4;
    if (i < n4) {
        float4 v = ((float4*)x)[i];
        int c = ((i * 4) / HWSZ) % C;
        float mean = stats[c], rstd = stats[C + c];
        v.x = fmaxf(0.f, (v.x - mean) * rstd);
        v.y = fmaxf(0.f, (v.y - mean) * rstd);
        v.z = fmaxf(0.f, (v.z - mean) * rstd);
        v.w = fmaxf(0.f, (v.w - mean) * rstd);
        ((float4*)x)[i] = v;
    }
}

__global__ __launch_bounds__(256) void bn_pool(const float* __restrict__ x,
                                               const float* __restrict__ stats,
                                               float* __restrict__ out, int B,
                                               int C) {
    const int Ho = 64, Wo = 64;
    int i = blockIdx.x * blockDim.x + threadIdx.x;
    int total = B * C * Ho * Wo;
    if (i >= total) return;
    int ow = i % Wo;
    int t = i / Wo;
    int oh = t % Ho;
    t /= Ho;
    int c = t % C;
    int b = t / C;
    const float* p = x + ((size_t)(b * C + c)) * HWSZ + (2 * oh) * WW + 2 * ow;
    float m0 = fmaxf(p[0], p[1]);
    float m1 = fmaxf(p[WW], p[WW + 1]);
    float mx = fmaxf(m0, m1);
    out[i] = fmaxf(0.f, (mx - stats[c]) * stats[C + c]);
}

extern "C" void kernel_launch(void* const* d_in, const int* in_sizes, int n_in,
                              void* d_out, int out_size, void* d_ws,
                              size_t ws_size, hipStream_t stream) {
    (void)in_sizes;
    (void)n_in;
    (void)out_size;
    (void)ws_size;
    const float* x = (const float*)d_in[0];
    const float* w_off1 = (const float*)d_in[1];
    const float* b_off1 = (const float*)d_in[2];
    const float* w_mod1 = (const float*)d_in[3];
    const float* b_mod1 = (const float*)d_in[4];
    const float* w1 = (const float*)d_in[5];
    const float* w_off2 = (const float*)d_in[6];
    const float* b_off2 = (const float*)d_in[7];
    const float* w_mod2 = (const float*)d_in[8];
    const float* b_mod2 = (const float*)d_in[9];
    const float* w2 = (const float*)d_in[10];
    float* out = (float*)d_out;
    float* ws = (float*)d_ws;

    // KP1 = 672 (C=64, CP=72), KP2 = 1248 (C=128, CP=136)
    ushort* Wt1 = (ushort*)ws;                  // 128*672  ushorts = 43008 floats
    ushort* Wt2 = (ushort*)(ws + 43008);        // 128*1248 ushorts = 79872 floats
    float* dyb = ws + 43008 + 79872;            // 589824
    float* dxb = dyb + 589824;
    float* mob = dxb + 589824;
    float* h1 = mob + 589824;                   // 8388608
    float* h2 = h1 + 8388608;                   // 8388608
    float* praw = h2 + 8388608;                 // 256
    float* stats = praw + 256;                  // 256

    transpose_wpad<<<(128 * 672 + 255) / 256, 256, 0, stream>>>(w1, Wt1, 64, 72,
                                                                672);
    transpose_wpad<<<(128 * 1248 + 255) / 256, 256, 0, stream>>>(w2, Wt2, 128,
                                                                 136, 1248);

    // ---- stage 1 ----
    offmod_conv<64><<<512, 128, 0, stream>>>(x, w_off1, b_off1, w_mod1, b_mod1,
                                             dyb, dxb, mob);
    deform_mfma<64, 32><<<2048, 256, 0, stream>>>(x, dyb, dxb, mob, Wt1, h1);
    zero_stats<<<1, 256, 0, stream>>>(praw);
    bn_partial<<<1024, 256, 0, stream>>>(h1, praw);
    bn_finalize<<<1, 128, 0, stream>>>(praw, stats);
    bn_apply<<<8192, 256, 0, stream>>>(h1, stats, 4 * 128 * HWSZ, 128);

    // ---- stage 2 ----
    offmod_conv<128><<<512, 128, 0, stream>>>(h1, w_off2, b_off2, w_mod2,
                                              b_mod2, dyb, dxb, mob);
    deform_mfma<128, 16><<<4096, 256, 0, stream>>>(h1, dyb, dxb, mob, Wt2, h2);
    zero_stats<<<1, 256, 0, stream>>>(praw);
    bn_partial<<<1024, 256, 0, stream>>>(h2, praw);
    bn_finalize<<<1, 128, 0, stream>>>(praw, stats);
    bn_pool<<<8192, 256, 0, stream>>>(h2, stats, out, 4, 128);
}

// Round 3
// 687.918 us; speedup vs baseline: 2.5241x; 1.8697x over previous
//
#include <hip/hip_runtime.h>
#include <math.h>

#define HH 128
#define WW 128
#define HWSZ 16384

typedef __attribute__((ext_vector_type(8))) short short8;
typedef __attribute__((ext_vector_type(4))) float f32x4;
typedef unsigned short ushort;

__device__ __forceinline__ ushort f2bf(float f) {
    unsigned int u = __float_as_uint(f);
    unsigned int r = u + 0x7fffu + ((u >> 16) & 1u);
    return (ushort)(r >> 16);
}

// ---- weight transpose+pad for deform GEMM: w[o][c][k] -> wt[o][k*(C+8)+c] ----
__global__ void transpose_wpad(const float* __restrict__ w, ushort* __restrict__ wt,
                               int C, int CP, int KP) {
    int i = blockIdx.x * 256 + threadIdx.x;
    if (i >= 128 * KP) return;
    int o = i / KP, kq = i % KP;
    int k = kq / CP, c = kq % CP;
    float v = (k < 9 && c < C) ? w[(o * C + c) * 9 + k] : 0.f;
    wt[i] = f2bf(v);
}

// ---- combined offset+mod weights for offmod GEMM: rows 0..17 off, 18..26 mod,
// 27..31 zero; kappa = c*16 + k (taps 9..15 zero-padded) ----
__global__ void build_woff(const float* __restrict__ w_off,
                           const float* __restrict__ w_mod,
                           ushort* __restrict__ wt, int C) {
    int K = C * 16;
    int i = blockIdx.x * 256 + threadIdx.x;
    if (i >= 32 * K) return;
    int o = i / K, kap = i % K;
    int c = kap >> 4, k = kap & 15;
    float v = 0.f;
    if (k < 9) {
        if (o < 18) v = w_off[(o * C + c) * 9 + k];
        else if (o < 27) v = w_mod[((o - 18) * C + c) * 9 + k];
    }
    wt[i] = f2bf(v);
}

// ---- offset/mod conv as MFMA implicit GEMM, im2col in registers ----
// block = 256 thr = 4 waves; wave wv = m-tile of 16 pixels; 64 pixels/block.
// A frag: lane pixel = wv*16 + (lane&15); quad q: channel 2*kk + (q>>1),
// taps 0..7 (q even) or tap 8 + zeros (q odd). B from global (L2-resident).
template <int C>
__global__ __launch_bounds__(256) void offmod_mfma(
    const float* __restrict__ x, const ushort* __restrict__ wt,
    const float* __restrict__ b_off, const float* __restrict__ b_mod,
    float* __restrict__ dyb, float* __restrict__ dxb,
    float* __restrict__ mob) {
    constexpr int K = C * 16;
    const int m0 = blockIdx.x * 64;
    const int b = m0 >> 14;
    const int hw0 = m0 & 16383;
    const int h = hw0 >> 7;   // uniform: block = 64 pixels within one row
    const int w0 = hw0 & 127;
    const int tid = threadIdx.x;
    const int lane = tid & 63, wv = tid >> 6;
    const int n16 = lane & 15, quad = lane >> 4;

    const int p = wv * 16 + n16;  // this lane's pixel (A row m)
    const int w = w0 + p;
    const int cq = quad >> 1;     // which channel of the pair
    const bool hi = (quad & 1);   // taps 8..15 half

    const float* xb = x + ((size_t)b * C << 14);

    f32x4 acc[2];
    acc[0] = (f32x4){0.f, 0.f, 0.f, 0.f};
    acc[1] = (f32x4){0.f, 0.f, 0.f, 0.f};

    const int yT = h - 1, yB = h + 1;
    const bool yTok = (yT >= 0), yBok = (yB < HH);
    const bool xLok = (w - 1 >= 0), xRok = (w + 1 < WW);

#pragma unroll 4
    for (int kk = 0; kk < C / 2; ++kk) {
        const float* xc = xb + ((size_t)(kk * 2 + cq) << 14);
        short8 a;
        if (!hi) {
            // taps 0..7: (ky,kx) = (0,0)(0,1)(0,2)(1,0)(1,1)(1,2)(2,0)(2,1)
            const float* r0 = xc + yT * WW + w;
            const float* r1 = xc + h * WW + w;
            const float* r2 = xc + yB * WW + w;
            float t0 = (yTok && xLok) ? r0[-1] : 0.f;
            float t1 = yTok ? r0[0] : 0.f;
            float t2 = (yTok && xRok) ? r0[1] : 0.f;
            float t3 = xLok ? r1[-1] : 0.f;
            float t4 = r1[0];
            float t5 = xRok ? r1[1] : 0.f;
            float t6 = (yBok && xLok) ? r2[-1] : 0.f;
            float t7 = yBok ? r2[0] : 0.f;
            a[0] = (short)f2bf(t0);
            a[1] = (short)f2bf(t1);
            a[2] = (short)f2bf(t2);
            a[3] = (short)f2bf(t3);
            a[4] = (short)f2bf(t4);
            a[5] = (short)f2bf(t5);
            a[6] = (short)f2bf(t6);
            a[7] = (short)f2bf(t7);
        } else {
            // tap 8: (2,2); taps 9..15 are zero padding
            float t8 = (yBok && xRok) ? xc[yB * WW + w + 1] : 0.f;
            a = (short8){0, 0, 0, 0, 0, 0, 0, 0};
            a[0] = (short)f2bf(t8);
        }
        const short8 b0 = *(const short8*)(wt + (size_t)n16 * K + kk * 32 + quad * 8);
        const short8 b1 =
            *(const short8*)(wt + (size_t)(16 + n16) * K + kk * 32 + quad * 8);
        acc[0] = __builtin_amdgcn_mfma_f32_16x16x32_bf16(a, b0, acc[0], 0, 0, 0);
        acc[1] = __builtin_amdgcn_mfma_f32_16x16x32_bf16(a, b1, acc[1], 0, 0, 0);
    }

    // ---- epilogue: transpose via LDS, coalesced stores with bias/sigmoid ----
    __shared__ float sm[32 * 65];
#pragma unroll
    for (int nt = 0; nt < 2; ++nt) {
        int n = nt * 16 + n16;
        int pb = wv * 16 + quad * 4;
#pragma unroll
        for (int r = 0; r < 4; ++r) sm[n * 65 + pb + r] = acc[nt][r];
    }
    __syncthreads();
    {
        int n = tid >> 3, i8 = tid & 7;  // n: 0..31, 8 pixels per thread
        if (n < 27) {
            const float* sp = sm + n * 65 + i8 * 8;
            int px = hw0 + i8 * 8;
            if (n < 18) {
                int k = n >> 1;
                float bias = b_off[n];
                float* dst =
                    ((n & 1) ? dxb : dyb) + (((size_t)(b * 9 + k)) << 14) + px;
#pragma unroll
                for (int j = 0; j < 8; j += 4) {
                    float4 v = make_float4(sp[j] + bias, sp[j + 1] + bias,
                                           sp[j + 2] + bias, sp[j + 3] + bias);
                    *(float4*)(dst + j) = v;
                }
            } else {
                float bias = b_mod[n - 18];
                float* dst = mob + (((size_t)(b * 9 + (n - 18))) << 14) + px;
#pragma unroll
                for (int j = 0; j < 8; j += 4) {
                    float4 v;
                    v.x = 2.f / (1.f + expf(-(sp[j] + bias)));
                    v.y = 2.f / (1.f + expf(-(sp[j + 1] + bias)));
                    v.z = 2.f / (1.f + expf(-(sp[j + 2] + bias)));
                    v.w = 2.f / (1.f + expf(-(sp[j + 3] + bias)));
                    *(float4*)(dst + j) = v;
                }
            }
        }
    }
}

// ---- deformable conv: lane-coherent gather + bf16 MFMA implicit GEMM ----
template <int C, int PIX>
__global__ __launch_bounds__(256) void deform_mfma(
    const float* __restrict__ x, const float* __restrict__ dyb,
    const float* __restrict__ dxb, const float* __restrict__ mob,
    const ushort* __restrict__ wt, float* __restrict__ out) {
    constexpr int CP = C + 8;
    constexpr int K9 = 9 * CP;
    constexpr int KP = ((K9 + 31) / 32) * 32;
    constexpr int ROWE = KP + 8;
    constexpr int MT = PIX / 16;
    constexpr int GG = 256 / PIX;
    constexpr int NP = 9 * C / GG;

    __shared__ __align__(16) ushort patch[PIX * ROWE];

    const int m0 = blockIdx.x * PIX;
    const int b = m0 >> 14;
    const int hw0 = m0 & 16383;
    const int h = hw0 >> 7, w0 = hw0 & 127;
    const int tid = threadIdx.x;

    for (int r = tid; r < PIX * 9; r += 256) {
        int p = r / 9, k = r % 9;
        *(uint4*)&patch[p * ROWE + k * CP + C] = uint4{0, 0, 0, 0};
    }
    if (tid < PIX) {
        uint4* t4 = (uint4*)&patch[tid * ROWE + K9];
        t4[0] = uint4{0, 0, 0, 0};
        t4[1] = uint4{0, 0, 0, 0};
        t4[2] = uint4{0, 0, 0, 0};
    }

    {
        const int p = tid % PIX, g = tid / PIX;
        const int w = w0 + p;
        const float* xb = x + ((size_t)b * C << 14);
        ushort* prow = patch + p * ROWE;
        const int pi0 = g * NP, pi1 = pi0 + NP;
        for (int k = pi0 / C; k * C < pi1; ++k) {
            int c0 = (k * C < pi0) ? (pi0 - k * C) : 0;
            int c1 = (pi1 - k * C < C) ? (pi1 - k * C) : C;
            int oi = ((b * 9 + k) << 14) + hw0 + p;
            float py = (float)(h + k / 3 - 1) + dyb[oi];
            float px = (float)(w + k % 3 - 1) + dxb[oi];
            float mv = mob[oi];
            float y0f = floorf(py), x0f = floorf(px);
            float wy = py - y0f, wx = px - x0f;
            int y0 = (int)y0f, x0 = (int)x0f;
            int y1 = y0 + 1, x1 = x0 + 1;
            float f00 = (1.f - wy) * (1.f - wx) *
                        (((unsigned)y0 < 128u && (unsigned)x0 < 128u) ? mv : 0.f);
            float f01 = (1.f - wy) * wx *
                        (((unsigned)y0 < 128u && (unsigned)x1 < 128u) ? mv : 0.f);
            float f10 = wy * (1.f - wx) *
                        (((unsigned)y1 < 128u && (unsigned)x0 < 128u) ? mv : 0.f);
            float f11 = wy * wx *
                        (((unsigned)y1 < 128u && (unsigned)x1 < 128u) ? mv : 0.f);
            int cy0 = min(max(y0, 0), 127), cy1 = min(max(y1, 0), 127);
            int cx0 = min(max(x0, 0), 127), cx1 = min(max(x1, 0), 127);
            int i00 = (cy0 << 7) + cx0, i01 = (cy0 << 7) + cx1;
            int i10 = (cy1 << 7) + cx0, i11 = (cy1 << 7) + cx1;
            ushort* pk = prow + k * CP;
#pragma unroll 4
            for (int c = c0; c < c1; ++c) {
                const float* xc = xb + ((size_t)c << 14);
                float v = f00 * xc[i00] + f01 * xc[i01] + f10 * xc[i10] +
                          f11 * xc[i11];
                pk[c] = f2bf(v);
            }
        }
    }
    __syncthreads();

    const int lane = tid & 63, wv = tid >> 6;
    const int n16 = lane & 15, quad = lane >> 4;

    f32x4 acc[MT][2];
#pragma unroll
    for (int mt = 0; mt < MT; ++mt)
#pragma unroll
        for (int nt = 0; nt < 2; ++nt) acc[mt][nt] = (f32x4){0.f, 0.f, 0.f, 0.f};

    const ushort* ap[MT];
#pragma unroll
    for (int mt = 0; mt < MT; ++mt)
        ap[mt] = patch + (mt * 16 + n16) * ROWE + quad * 8;
    const ushort* bp[2];
#pragma unroll
    for (int nt = 0; nt < 2; ++nt)
        bp[nt] = wt + (size_t)(wv * 32 + nt * 16 + n16) * KP + quad * 8;

    short8 a_c[MT], b_c[2];
#pragma unroll
    for (int mt = 0; mt < MT; ++mt) a_c[mt] = *(const short8*)(ap[mt]);
#pragma unroll
    for (int nt = 0; nt < 2; ++nt) b_c[nt] = *(const short8*)(bp[nt]);

    int kk = 0;
#pragma unroll 1
    for (; kk + 32 < KP; kk += 32) {
        short8 a_n[MT], b_n[2];
#pragma unroll
        for (int mt = 0; mt < MT; ++mt)
            a_n[mt] = *(const short8*)(ap[mt] + kk + 32);
#pragma unroll
        for (int nt = 0; nt < 2; ++nt)
            b_n[nt] = *(const short8*)(bp[nt] + kk + 32);
#pragma unroll
        for (int mt = 0; mt < MT; ++mt)
#pragma unroll
            for (int nt = 0; nt < 2; ++nt)
                acc[mt][nt] = __builtin_amdgcn_mfma_f32_16x16x32_bf16(
                    a_c[mt], b_c[nt], acc[mt][nt], 0, 0, 0);
#pragma unroll
        for (int mt = 0; mt < MT; ++mt) a_c[mt] = a_n[mt];
#pragma unroll
        for (int nt = 0; nt < 2; ++nt) b_c[nt] = b_n[nt];
    }
#pragma unroll
    for (int mt = 0; mt < MT; ++mt)
#pragma unroll
        for (int nt = 0; nt < 2; ++nt)
            acc[mt][nt] = __builtin_amdgcn_mfma_f32_16x16x32_bf16(
                a_c[mt], b_c[nt], acc[mt][nt], 0, 0, 0);

    __syncthreads();
    float* sm = (float*)patch;
    constexpr int SROW = PIX + 1;
#pragma unroll
    for (int mt = 0; mt < MT; ++mt)
#pragma unroll
        for (int nt = 0; nt < 2; ++nt) {
            int o = wv * 32 + nt * 16 + n16;
            int mb = mt * 16 + quad * 4;
#pragma unroll
            for (int r = 0; r < 4; ++r) sm[o * SROW + mb + r] = acc[mt][nt][r];
        }
    __syncthreads();
    {
        int o = tid >> 1, half = tid & 1;
        constexpr int HP = PIX / 2;
        const float* sp = sm + o * SROW + half * HP;
        float* op = out + (((size_t)(b * 128 + o)) << 14) + hw0 + half * HP;
#pragma unroll
        for (int i = 0; i < HP; i += 4) {
            float4 v = make_float4(sp[i], sp[i + 1], sp[i + 2], sp[i + 3]);
            *(float4*)(op + i) = v;
        }
    }
}

// ---- bn stats: split grid + float atomics ----
__global__ __launch_bounds__(256) void zero_stats(float* __restrict__ praw) {
    praw[threadIdx.x] = 0.f;
}

__global__ __launch_bounds__(256) void bn_partial(const float* __restrict__ xin,
                                                  float* __restrict__ praw) {
    int c = blockIdx.x >> 3, s = blockIdx.x & 7;
    float su = 0.f, sq = 0.f;
#pragma unroll
    for (int j = 0; j < 8; ++j) {
        int e = s * 8192 + (j * 256 + threadIdx.x) * 4;
        int b = e >> 14, hw = e & 16383;
        const float4 v =
            *(const float4*)(xin + (((size_t)(b * 128 + c)) << 14) + hw);
        su += v.x + v.y + v.z + v.w;
        sq += v.x * v.x + v.y * v.y + v.z * v.z + v.w * v.w;
    }
#pragma unroll
    for (int off = 32; off > 0; off >>= 1) {
        su += __shfl_down(su, off, 64);
        sq += __shfl_down(sq, off, 64);
    }
    if ((threadIdx.x & 63) == 0) {
        atomicAdd(&praw[c], su);
        atomicAdd(&praw[128 + c], sq);
    }
}

__global__ __launch_bounds__(128) void bn_finalize(const float* __restrict__ praw,
                                                   float* __restrict__ stats) {
    int c = threadIdx.x;
    float N = 65536.f;
    float mean = praw[c] / N;
    float var = praw[128 + c] / N - mean * mean;
    stats[c] = mean;
    stats[128 + c] = rsqrtf(var + 1e-5f);
}

__global__ __launch_bounds__(256) void bn_apply(float* __restrict__ x,
                                                const float* __restrict__ stats,
                                                int total, int C) {
    int i = blockIdx.x * blockDim.x + threadIdx.x;
    int n4 = total / 4;
    if (i < n4) {
        float4 v = ((float4*)x)[i];
        int c = ((i * 4) / HWSZ) % C;
        float mean = stats[c], rstd = stats[C + c];
        v.x = fmaxf(0.f, (v.x - mean) * rstd);
        v.y = fmaxf(0.f, (v.y - mean) * rstd);
        v.z = fmaxf(0.f, (v.z - mean) * rstd);
        v.w = fmaxf(0.f, (v.w - mean) * rstd);
        ((float4*)x)[i] = v;
    }
}

__global__ __launch_bounds__(256) void bn_pool(const float* __restrict__ x,
                                               const float* __restrict__ stats,
                                               float* __restrict__ out, int B,
                                               int C) {
    const int Ho = 64, Wo = 64;
    int i = blockIdx.x * blockDim.x + threadIdx.x;
    int total = B * C * Ho * Wo;
    if (i >= total) return;
    int ow = i % Wo;
    int t = i / Wo;
    int oh = t % Ho;
    t /= Ho;
    int c = t % C;
    int b = t / C;
    const float* p = x + ((size_t)(b * C + c)) * HWSZ + (2 * oh) * WW + 2 * ow;
    float m0 = fmaxf(p[0], p[1]);
    float m1 = fmaxf(p[WW], p[WW + 1]);
    float mx = fmaxf(m0, m1);
    out[i] = fmaxf(0.f, (mx - stats[c]) * stats[C + c]);
}

extern "C" void kernel_launch(void* const* d_in, const int* in_sizes, int n_in,
                              void* d_out, int out_size, void* d_ws,
                              size_t ws_size, hipStream_t stream) {
    (void)in_sizes;
    (void)n_in;
    (void)out_size;
    (void)ws_size;
    const float* x = (const float*)d_in[0];
    const float* w_off1 = (const float*)d_in[1];
    const float* b_off1 = (const float*)d_in[2];
    const float* w_mod1 = (const float*)d_in[3];
    const float* b_mod1 = (const float*)d_in[4];
    const float* w1 = (const float*)d_in[5];
    const float* w_off2 = (const float*)d_in[6];
    const float* b_off2 = (const float*)d_in[7];
    const float* w_mod2 = (const float*)d_in[8];
    const float* b_mod2 = (const float*)d_in[9];
    const float* w2 = (const float*)d_in[10];
    float* out = (float*)d_out;
    float* ws = (float*)d_ws;

    // KP1 = 672 (C=64, CP=72), KP2 = 1248 (C=128, CP=136)
    ushort* Wt1 = (ushort*)ws;                        // 86016 ush = 43008 f
    ushort* Wt2 = (ushort*)(ws + 43008);              // 159744 ush = 79872 f
    ushort* Wo1 = (ushort*)(ws + 43008 + 79872);      // 32*1024 ush = 16384 f
    ushort* Wo2 = (ushort*)(ws + 43008 + 79872 + 16384);  // 32*2048 = 32768 f
    float* dyb = ws + 172032;
    float* dxb = dyb + 589824;
    float* mob = dxb + 589824;
    float* h1 = mob + 589824;
    float* h2 = h1 + 8388608;
    float* praw = h2 + 8388608;
    float* stats = praw + 256;

    transpose_wpad<<<(128 * 672 + 255) / 256, 256, 0, stream>>>(w1, Wt1, 64, 72,
                                                                672);
    transpose_wpad<<<(128 * 1248 + 255) / 256, 256, 0, stream>>>(w2, Wt2, 128,
                                                                 136, 1248);
    build_woff<<<128, 256, 0, stream>>>(w_off1, w_mod1, Wo1, 64);
    build_woff<<<256, 256, 0, stream>>>(w_off2, w_mod2, Wo2, 128);

    // ---- stage 1 ----
    offmod_mfma<64><<<1024, 256, 0, stream>>>(x, Wo1, b_off1, b_mod1, dyb, dxb,
                                              mob);
    deform_mfma<64, 32><<<2048, 256, 0, stream>>>(x, dyb, dxb, mob, Wt1, h1);
    zero_stats<<<1, 256, 0, stream>>>(praw);
    bn_partial<<<1024, 256, 0, stream>>>(h1, praw);
    bn_finalize<<<1, 128, 0, stream>>>(praw, stats);
    bn_apply<<<8192, 256, 0, stream>>>(h1, stats, 4 * 128 * HWSZ, 128);

    // ---- stage 2 ----
    offmod_mfma<128><<<1024, 256, 0, stream>>>(h1, Wo2, b_off2, b_mod2, dyb,
                                               dxb, mob);
    deform_mfma<128, 16><<<4096, 256, 0, stream>>>(h1, dyb, dxb, mob, Wt2, h2);
    zero_stats<<<1, 256, 0, stream>>>(praw);
    bn_partial<<<1024, 256, 0, stream>>>(h2, praw);
    bn_finalize<<<1, 128, 0, stream>>>(praw, stats);
    bn_pool<<<8192, 256, 0, stream>>>(h2, stats, out, 4, 128);
}

// Round 4
// 478.109 us; speedup vs baseline: 3.6318x; 1.4388x over previous
//
#include <hip/hip_runtime.h>
#include <math.h>

#define HH 128
#define WW 128
#define HWSZ 16384

typedef __attribute__((ext_vector_type(8))) short short8;
typedef __attribute__((ext_vector_type(4))) float f32x4;
typedef unsigned short ushort;

__device__ __forceinline__ ushort f2bf(float f) {
    unsigned int u = __float_as_uint(f);
    unsigned int r = u + 0x7fffu + ((u >> 16) & 1u);
    return (ushort)(r >> 16);
}

// ---- weight transpose+pad for deform GEMM: w[o][c][k] -> wt[o][k*(C+8)+c] ----
__global__ void transpose_wpad(const float* __restrict__ w, ushort* __restrict__ wt,
                               int C, int CP, int KP) {
    int i = blockIdx.x * 256 + threadIdx.x;
    if (i >= 128 * KP) return;
    int o = i / KP, kq = i % KP;
    int k = kq / CP, c = kq % CP;
    float v = (k < 9 && c < C) ? w[(o * C + c) * 9 + k] : 0.f;
    wt[i] = f2bf(v);
}

// ---- combined offset+mod weights for offmod GEMM ----
__global__ void build_woff(const float* __restrict__ w_off,
                           const float* __restrict__ w_mod,
                           ushort* __restrict__ wt, int C) {
    int K = C * 16;
    int i = blockIdx.x * 256 + threadIdx.x;
    if (i >= 32 * K) return;
    int o = i / K, kap = i % K;
    int c = kap >> 4, k = kap & 15;
    float v = 0.f;
    if (k < 9) {
        if (o < 18) v = w_off[(o * C + c) * 9 + k];
        else if (o < 27) v = w_mod[((o - 18) * C + c) * 9 + k];
    }
    wt[i] = f2bf(v);
}

// ---- NCHW fp32 -> NHWC bf16 converter (tiled transpose) ----
// block: 64 pixels x C channels
template <int C>
__global__ __launch_bounds__(256) void nhwc_cvt(const float* __restrict__ xin,
                                                unsigned* __restrict__ xout) {
    __shared__ float tile[64][C + 1];
    const int m0 = blockIdx.x * 64;  // global pixel (b*16384+hw)
    const int b = m0 >> 14;
    const int hw0 = m0 & 16383;
    const int t = threadIdx.x;
    const int pr = t & 63, cr = t >> 6;  // read: lanes along pixels
#pragma unroll
    for (int it = 0; it < C / 4; ++it) {
        int c = it * 4 + cr;
        tile[pr][c] = xin[(((size_t)(b * C + c)) << 14) + hw0 + pr];
    }
    __syncthreads();
    constexpr int CH = C / 2;  // ushort2 slots per pixel
#pragma unroll
    for (int it = 0; it < 64 * CH / 256; ++it) {
        int slot = it * 256 + t;
        int p = slot / CH, cc = slot % CH;
        unsigned lo = f2bf(tile[p][2 * cc]);
        unsigned hi = f2bf(tile[p][2 * cc + 1]);
        xout[(size_t)(m0 + p) * CH + cc] = lo | (hi << 16);
    }
}

// ---- offset/mod conv as MFMA implicit GEMM, im2col in registers ----
template <int C>
__global__ __launch_bounds__(256) void offmod_mfma(
    const float* __restrict__ x, const ushort* __restrict__ wt,
    const float* __restrict__ b_off, const float* __restrict__ b_mod,
    float* __restrict__ dyb, float* __restrict__ dxb,
    float* __restrict__ mob) {
    constexpr int K = C * 16;
    const int m0 = blockIdx.x * 64;
    const int b = m0 >> 14;
    const int hw0 = m0 & 16383;
    const int h = hw0 >> 7;
    const int w0 = hw0 & 127;
    const int tid = threadIdx.x;
    const int lane = tid & 63, wv = tid >> 6;
    const int n16 = lane & 15, quad = lane >> 4;

    const int p = wv * 16 + n16;
    const int w = w0 + p;
    const int cq = quad >> 1;
    const bool hi = (quad & 1);

    const float* xb = x + ((size_t)b * C << 14);

    f32x4 acc[2];
    acc[0] = (f32x4){0.f, 0.f, 0.f, 0.f};
    acc[1] = (f32x4){0.f, 0.f, 0.f, 0.f};

    const int yT = h - 1, yB = h + 1;
    const bool yTok = (yT >= 0), yBok = (yB < HH);
    const bool xLok = (w - 1 >= 0), xRok = (w + 1 < WW);

#pragma unroll 4
    for (int kk = 0; kk < C / 2; ++kk) {
        const float* xc = xb + ((size_t)(kk * 2 + cq) << 14);
        short8 a;
        if (!hi) {
            const float* r0 = xc + yT * WW + w;
            const float* r1 = xc + h * WW + w;
            const float* r2 = xc + yB * WW + w;
            float t0 = (yTok && xLok) ? r0[-1] : 0.f;
            float t1 = yTok ? r0[0] : 0.f;
            float t2 = (yTok && xRok) ? r0[1] : 0.f;
            float t3 = xLok ? r1[-1] : 0.f;
            float t4 = r1[0];
            float t5 = xRok ? r1[1] : 0.f;
            float t6 = (yBok && xLok) ? r2[-1] : 0.f;
            float t7 = yBok ? r2[0] : 0.f;
            a[0] = (short)f2bf(t0);
            a[1] = (short)f2bf(t1);
            a[2] = (short)f2bf(t2);
            a[3] = (short)f2bf(t3);
            a[4] = (short)f2bf(t4);
            a[5] = (short)f2bf(t5);
            a[6] = (short)f2bf(t6);
            a[7] = (short)f2bf(t7);
        } else {
            float t8 = (yBok && xRok) ? xc[yB * WW + w + 1] : 0.f;
            a = (short8){0, 0, 0, 0, 0, 0, 0, 0};
            a[0] = (short)f2bf(t8);
        }
        const short8 b0 = *(const short8*)(wt + (size_t)n16 * K + kk * 32 + quad * 8);
        const short8 b1 =
            *(const short8*)(wt + (size_t)(16 + n16) * K + kk * 32 + quad * 8);
        acc[0] = __builtin_amdgcn_mfma_f32_16x16x32_bf16(a, b0, acc[0], 0, 0, 0);
        acc[1] = __builtin_amdgcn_mfma_f32_16x16x32_bf16(a, b1, acc[1], 0, 0, 0);
    }

    __shared__ float sm[32 * 65];
#pragma unroll
    for (int nt = 0; nt < 2; ++nt) {
        int n = nt * 16 + n16;
        int pb = wv * 16 + quad * 4;
#pragma unroll
        for (int r = 0; r < 4; ++r) sm[n * 65 + pb + r] = acc[nt][r];
    }
    __syncthreads();
    {
        int n = tid >> 3, i8 = tid & 7;
        if (n < 27) {
            const float* sp = sm + n * 65 + i8 * 8;
            int px = hw0 + i8 * 8;
            if (n < 18) {
                int k = n >> 1;
                float bias = b_off[n];
                float* dst =
                    ((n & 1) ? dxb : dyb) + (((size_t)(b * 9 + k)) << 14) + px;
#pragma unroll
                for (int j = 0; j < 8; j += 4) {
                    float4 v = make_float4(sp[j] + bias, sp[j + 1] + bias,
                                           sp[j + 2] + bias, sp[j + 3] + bias);
                    *(float4*)(dst + j) = v;
                }
            } else {
                float bias = b_mod[n - 18];
                float* dst = mob + (((size_t)(b * 9 + (n - 18))) << 14) + px;
#pragma unroll
                for (int j = 0; j < 8; j += 4) {
                    float4 v;
                    v.x = 2.f / (1.f + expf(-(sp[j] + bias)));
                    v.y = 2.f / (1.f + expf(-(sp[j + 1] + bias)));
                    v.z = 2.f / (1.f + expf(-(sp[j + 2] + bias)));
                    v.w = 2.f / (1.f + expf(-(sp[j + 3] + bias)));
                    *(float4*)(dst + j) = v;
                }
            }
        }
    }
}

// ---- deformable conv: NHWC-bf16 vectorized gather + bf16 MFMA ----
// tap params precomputed once per (p,k) into LDS; gather loads ushort8 over c.
template <int C, int PIX>
__global__ __launch_bounds__(256) void deform_mfma(
    const ushort* __restrict__ xh, const float* __restrict__ dyb,
    const float* __restrict__ dxb, const float* __restrict__ mob,
    const ushort* __restrict__ wt, float* __restrict__ out) {
    constexpr int CP = C + 8;
    constexpr int K9 = 9 * CP;
    constexpr int KP = ((K9 + 31) / 32) * 32;
    constexpr int ROWE = KP + 8;
    constexpr int MT = PIX / 16;
    constexpr int NCC = C / 8;             // ushort8 chunks per (p,k)
    constexpr int NCHUNK = PIX * 9 * NCC;  // 2304 for both stages
    static_assert(NCHUNK % 256 == 0, "chunk count");

    __shared__ __align__(16) ushort patch[PIX * ROWE];
    __shared__ __align__(16) int tbase[PIX * 9 * 4];
    __shared__ __align__(16) float twt[PIX * 9 * 4];

    const int m0 = blockIdx.x * PIX;
    const int b = m0 >> 14;
    const int hw0 = m0 & 16383;
    const int h = hw0 >> 7, w0 = hw0 & 127;
    const int tid = threadIdx.x;

    // zero pads: c-pad per (p,k) and k-tail per p
    for (int r = tid; r < PIX * 9; r += 256) {
        int p = r / 9, k = r % 9;
        *(uint4*)&patch[p * ROWE + k * CP + C] = uint4{0, 0, 0, 0};
    }
    if (tid < PIX) {
        uint4* t4 = (uint4*)&patch[tid * ROWE + K9];
        t4[0] = uint4{0, 0, 0, 0};
        t4[1] = uint4{0, 0, 0, 0};
        t4[2] = uint4{0, 0, 0, 0};
    }

    // tap setup: one (p,k) per thread slot
    for (int r = tid; r < PIX * 9; r += 256) {
        int p = r / 9, k = r % 9;
        int oi = ((b * 9 + k) << 14) + hw0 + p;
        float py = (float)(h + k / 3 - 1) + dyb[oi];
        float px = (float)(w0 + p + k % 3 - 1) + dxb[oi];
        float mv = mob[oi];
        float y0f = floorf(py), x0f = floorf(px);
        float wy = py - y0f, wx = px - x0f;
        int y0 = (int)y0f, x0 = (int)x0f;
        int y1 = y0 + 1, x1 = x0 + 1;
        float f00 = (1.f - wy) * (1.f - wx) *
                    (((unsigned)y0 < 128u && (unsigned)x0 < 128u) ? mv : 0.f);
        float f01 = (1.f - wy) * wx *
                    (((unsigned)y0 < 128u && (unsigned)x1 < 128u) ? mv : 0.f);
        float f10 = wy * (1.f - wx) *
                    (((unsigned)y1 < 128u && (unsigned)x0 < 128u) ? mv : 0.f);
        float f11 = wy * wx *
                    (((unsigned)y1 < 128u && (unsigned)x1 < 128u) ? mv : 0.f);
        int cy0 = min(max(y0, 0), 127), cy1 = min(max(y1, 0), 127);
        int cx0 = min(max(x0, 0), 127), cx1 = min(max(x1, 0), 127);
        int bpx = b << 14;
        tbase[r * 4 + 0] = (bpx + (cy0 << 7) + cx0) * C;
        tbase[r * 4 + 1] = (bpx + (cy0 << 7) + cx1) * C;
        tbase[r * 4 + 2] = (bpx + (cy1 << 7) + cx0) * C;
        tbase[r * 4 + 3] = (bpx + (cy1 << 7) + cx1) * C;
        twt[r * 4 + 0] = f00;
        twt[r * 4 + 1] = f01;
        twt[r * 4 + 2] = f10;
        twt[r * 4 + 3] = f11;
    }
    __syncthreads();

    // gather: ushort8 (16B) per tap over 8 channels
#pragma unroll 3
    for (int it = 0; it < NCHUNK / 256; ++it) {
        int e = it * 256 + tid;
        int pair = e / NCC, cc = e % NCC;
        int4 bi = *(const int4*)&tbase[pair * 4];
        float4 fw = *(const float4*)&twt[pair * 4];
        uint4 q0 = *(const uint4*)(xh + (size_t)bi.x + cc * 8);
        uint4 q1 = *(const uint4*)(xh + (size_t)bi.y + cc * 8);
        uint4 q2 = *(const uint4*)(xh + (size_t)bi.z + cc * 8);
        uint4 q3 = *(const uint4*)(xh + (size_t)bi.w + cc * 8);
        unsigned a0[4] = {q0.x, q0.y, q0.z, q0.w};
        unsigned a1[4] = {q1.x, q1.y, q1.z, q1.w};
        unsigned a2[4] = {q2.x, q2.y, q2.z, q2.w};
        unsigned a3[4] = {q3.x, q3.y, q3.z, q3.w};
        unsigned ov[4];
#pragma unroll
        for (int dw = 0; dw < 4; ++dw) {
            float lo = fw.x * __uint_as_float(a0[dw] << 16) +
                       fw.y * __uint_as_float(a1[dw] << 16) +
                       fw.z * __uint_as_float(a2[dw] << 16) +
                       fw.w * __uint_as_float(a3[dw] << 16);
            float hv = fw.x * __uint_as_float(a0[dw] & 0xffff0000u) +
                       fw.y * __uint_as_float(a1[dw] & 0xffff0000u) +
                       fw.z * __uint_as_float(a2[dw] & 0xffff0000u) +
                       fw.w * __uint_as_float(a3[dw] & 0xffff0000u);
            unsigned rlo = f2bf(lo), rhi = f2bf(hv);
            ov[dw] = rlo | (rhi << 16);
        }
        int p = pair / 9, k = pair % 9;
        *(uint4*)&patch[p * ROWE + k * CP + cc * 8] =
            uint4{ov[0], ov[1], ov[2], ov[3]};
    }
    __syncthreads();

    // ---- MFMA phase ----
    const int lane = tid & 63, wv = tid >> 6;
    const int n16 = lane & 15, quad = lane >> 4;

    f32x4 acc[MT][2];
#pragma unroll
    for (int mt = 0; mt < MT; ++mt)
#pragma unroll
        for (int nt = 0; nt < 2; ++nt) acc[mt][nt] = (f32x4){0.f, 0.f, 0.f, 0.f};

    const ushort* ap[MT];
#pragma unroll
    for (int mt = 0; mt < MT; ++mt)
        ap[mt] = patch + (mt * 16 + n16) * ROWE + quad * 8;
    const ushort* bp[2];
#pragma unroll
    for (int nt = 0; nt < 2; ++nt)
        bp[nt] = wt + (size_t)(wv * 32 + nt * 16 + n16) * KP + quad * 8;

    short8 a_c[MT], b_c[2];
#pragma unroll
    for (int mt = 0; mt < MT; ++mt) a_c[mt] = *(const short8*)(ap[mt]);
#pragma unroll
    for (int nt = 0; nt < 2; ++nt) b_c[nt] = *(const short8*)(bp[nt]);

    int kk = 0;
#pragma unroll 1
    for (; kk + 32 < KP; kk += 32) {
        short8 a_n[MT], b_n[2];
#pragma unroll
        for (int mt = 0; mt < MT; ++mt)
            a_n[mt] = *(const short8*)(ap[mt] + kk + 32);
#pragma unroll
        for (int nt = 0; nt < 2; ++nt)
            b_n[nt] = *(const short8*)(bp[nt] + kk + 32);
#pragma unroll
        for (int mt = 0; mt < MT; ++mt)
#pragma unroll
            for (int nt = 0; nt < 2; ++nt)
                acc[mt][nt] = __builtin_amdgcn_mfma_f32_16x16x32_bf16(
                    a_c[mt], b_c[nt], acc[mt][nt], 0, 0, 0);
#pragma unroll
        for (int mt = 0; mt < MT; ++mt) a_c[mt] = a_n[mt];
#pragma unroll
        for (int nt = 0; nt < 2; ++nt) b_c[nt] = b_n[nt];
    }
#pragma unroll
    for (int mt = 0; mt < MT; ++mt)
#pragma unroll
        for (int nt = 0; nt < 2; ++nt)
            acc[mt][nt] = __builtin_amdgcn_mfma_f32_16x16x32_bf16(
                a_c[mt], b_c[nt], acc[mt][nt], 0, 0, 0);

    __syncthreads();
    float* sm = (float*)patch;
    constexpr int SROW = PIX + 1;
#pragma unroll
    for (int mt = 0; mt < MT; ++mt)
#pragma unroll
        for (int nt = 0; nt < 2; ++nt) {
            int o = wv * 32 + nt * 16 + n16;
            int mb = mt * 16 + quad * 4;
#pragma unroll
            for (int r = 0; r < 4; ++r) sm[o * SROW + mb + r] = acc[mt][nt][r];
        }
    __syncthreads();
    {
        int o = tid >> 1, half = tid & 1;
        constexpr int HP = PIX / 2;
        const float* sp = sm + o * SROW + half * HP;
        float* op = out + (((size_t)(b * 128 + o)) << 14) + hw0 + half * HP;
#pragma unroll
        for (int i = 0; i < HP; i += 4) {
            float4 v = make_float4(sp[i], sp[i + 1], sp[i + 2], sp[i + 3]);
            *(float4*)(op + i) = v;
        }
    }
}

// ---- bn stats: split grid + float atomics ----
__global__ __launch_bounds__(256) void zero_stats(float* __restrict__ praw) {
    praw[threadIdx.x] = 0.f;
}

__global__ __launch_bounds__(256) void bn_partial(const float* __restrict__ xin,
                                                  float* __restrict__ praw) {
    int c = blockIdx.x >> 3, s = blockIdx.x & 7;
    float su = 0.f, sq = 0.f;
#pragma unroll
    for (int j = 0; j < 8; ++j) {
        int e = s * 8192 + (j * 256 + threadIdx.x) * 4;
        int b = e >> 14, hw = e & 16383;
        const float4 v =
            *(const float4*)(xin + (((size_t)(b * 128 + c)) << 14) + hw);
        su += v.x + v.y + v.z + v.w;
        sq += v.x * v.x + v.y * v.y + v.z * v.z + v.w * v.w;
    }
#pragma unroll
    for (int off = 32; off > 0; off >>= 1) {
        su += __shfl_down(su, off, 64);
        sq += __shfl_down(sq, off, 64);
    }
    if ((threadIdx.x & 63) == 0) {
        atomicAdd(&praw[c], su);
        atomicAdd(&praw[128 + c], sq);
    }
}

__global__ __launch_bounds__(128) void bn_finalize(const float* __restrict__ praw,
                                                   float* __restrict__ stats) {
    int c = threadIdx.x;
    float N = 65536.f;
    float mean = praw[c] / N;
    float var = praw[128 + c] / N - mean * mean;
    stats[c] = mean;
    stats[128 + c] = rsqrtf(var + 1e-5f);
}

__global__ __launch_bounds__(256) void bn_apply(float* __restrict__ x,
                                                const float* __restrict__ stats,
                                                int total, int C) {
    int i = blockIdx.x * blockDim.x + threadIdx.x;
    int n4 = total / 4;
    if (i < n4) {
        float4 v = ((float4*)x)[i];
        int c = ((i * 4) / HWSZ) % C;
        float mean = stats[c], rstd = stats[C + c];
        v.x = fmaxf(0.f, (v.x - mean) * rstd);
        v.y = fmaxf(0.f, (v.y - mean) * rstd);
        v.z = fmaxf(0.f, (v.z - mean) * rstd);
        v.w = fmaxf(0.f, (v.w - mean) * rstd);
        ((float4*)x)[i] = v;
    }
}

__global__ __launch_bounds__(256) void bn_pool(const float* __restrict__ x,
                                               const float* __restrict__ stats,
                                               float* __restrict__ out, int B,
                                               int C) {
    const int Ho = 64, Wo = 64;
    int i = blockIdx.x * blockDim.x + threadIdx.x;
    int total = B * C * Ho * Wo;
    if (i >= total) return;
    int ow = i % Wo;
    int t = i / Wo;
    int oh = t % Ho;
    t /= Ho;
    int c = t % C;
    int b = t / C;
    const float* p = x + ((size_t)(b * C + c)) * HWSZ + (2 * oh) * WW + 2 * ow;
    float m0 = fmaxf(p[0], p[1]);
    float m1 = fmaxf(p[WW], p[WW + 1]);
    float mx = fmaxf(m0, m1);
    out[i] = fmaxf(0.f, (mx - stats[c]) * stats[C + c]);
}

extern "C" void kernel_launch(void* const* d_in, const int* in_sizes, int n_in,
                              void* d_out, int out_size, void* d_ws,
                              size_t ws_size, hipStream_t stream) {
    (void)in_sizes;
    (void)n_in;
    (void)out_size;
    (void)ws_size;
    const float* x = (const float*)d_in[0];
    const float* w_off1 = (const float*)d_in[1];
    const float* b_off1 = (const float*)d_in[2];
    const float* w_mod1 = (const float*)d_in[3];
    const float* b_mod1 = (const float*)d_in[4];
    const float* w1 = (const float*)d_in[5];
    const float* w_off2 = (const float*)d_in[6];
    const float* b_off2 = (const float*)d_in[7];
    const float* w_mod2 = (const float*)d_in[8];
    const float* b_mod2 = (const float*)d_in[9];
    const float* w2 = (const float*)d_in[10];
    float* out = (float*)d_out;
    float* ws = (float*)d_ws;

    // KP1 = 672 (C=64, CP=72), KP2 = 1248 (C=128, CP=136)
    ushort* Wt1 = (ushort*)ws;                            // 43008 f
    ushort* Wt2 = (ushort*)(ws + 43008);                  // 79872 f
    ushort* Wo1 = (ushort*)(ws + 43008 + 79872);          // 16384 f
    ushort* Wo2 = (ushort*)(ws + 43008 + 79872 + 16384);  // 32768 f
    float* dyb = ws + 172032;
    float* dxb = dyb + 589824;
    float* mob = dxb + 589824;
    float* hbuf = mob + 589824;      // 8388608 f: h1, later reused as h2
    float* xhf = hbuf + 8388608;     // 2097152 f: x as NHWC bf16
    float* h1hf = xhf + 2097152;     // 4194304 f: h1 as NHWC bf16
    float* praw = h1hf + 4194304;    // 256
    float* stats = praw + 256;       // 256
    ushort* xh = (ushort*)xhf;
    ushort* h1h = (ushort*)h1hf;

    transpose_wpad<<<(128 * 672 + 255) / 256, 256, 0, stream>>>(w1, Wt1, 64, 72,
                                                                672);
    transpose_wpad<<<(128 * 1248 + 255) / 256, 256, 0, stream>>>(w2, Wt2, 128,
                                                                 136, 1248);
    build_woff<<<128, 256, 0, stream>>>(w_off1, w_mod1, Wo1, 64);
    build_woff<<<256, 256, 0, stream>>>(w_off2, w_mod2, Wo2, 128);

    // ---- stage 1 ----
    nhwc_cvt<64><<<1024, 256, 0, stream>>>(x, (unsigned*)xh);
    offmod_mfma<64><<<1024, 256, 0, stream>>>(x, Wo1, b_off1, b_mod1, dyb, dxb,
                                              mob);
    deform_mfma<64, 32><<<2048, 256, 0, stream>>>(xh, dyb, dxb, mob, Wt1, hbuf);
    zero_stats<<<1, 256, 0, stream>>>(praw);
    bn_partial<<<1024, 256, 0, stream>>>(hbuf, praw);
    bn_finalize<<<1, 128, 0, stream>>>(praw, stats);
    bn_apply<<<8192, 256, 0, stream>>>(hbuf, stats, 4 * 128 * HWSZ, 128);

    // ---- stage 2 ----
    nhwc_cvt<128><<<1024, 256, 0, stream>>>(hbuf, (unsigned*)h1h);
    offmod_mfma<128><<<1024, 256, 0, stream>>>(hbuf, Wo2, b_off2, b_mod2, dyb,
                                               dxb, mob);
    // hbuf (h1) is dead after offmod+cvt: deform2 writes h2 into it
    deform_mfma<128, 16><<<4096, 256, 0, stream>>>(h1h, dyb, dxb, mob, Wt2,
                                                   hbuf);
    zero_stats<<<1, 256, 0, stream>>>(praw);
    bn_partial<<<1024, 256, 0, stream>>>(hbuf, praw);
    bn_finalize<<<1, 128, 0, stream>>>(praw, stats);
    bn_pool<<<8192, 256, 0, stream>>>(hbuf, stats, out, 4, 128);
}